// Round 2
// baseline (267.349 us; speedup 1.0000x reference)
//
#include <hip/hip_runtime.h>

// MHA forward, MI355X gfx950.
// B=2, S=2048, D=1024, H=16, DK=64. fp32 in/out, bf16 MFMA compute inside.
#define B_  2
#define S_  2048
#define D_  1024
#define H_  16
#define DK_ 64

using bf16x8 = __attribute__((ext_vector_type(8))) short;   // 8 bf16 in 4 VGPRs
using f32x4  = __attribute__((ext_vector_type(4))) float;

__device__ __forceinline__ unsigned short f2bf(float f) {
    unsigned u = __builtin_bit_cast(unsigned, f);
    u += 0x7FFFu + ((u >> 16) & 1u);            // RNE
    return (unsigned short)(u >> 16);
}

__device__ __forceinline__ void gload_lds16(const unsigned short* gsrc, unsigned short* ldst) {
    // 16B direct global->LDS. LDS dest must be wave-uniform base (+lane*16 implicit).
    __builtin_amdgcn_global_load_lds((const __attribute__((address_space(1))) void*)gsrc,
                                     (__attribute__((address_space(3))) void*)ldst, 16, 0, 0);
}

// ---------------------------------------------------------------- cast kernel
// Segments (1M-elem units): [0,4)Q [4,8)K [8,12)V [12]Wq [13]Wk [14]Wv [15]Wo
__global__ __launch_bounds__(256) void cast_all_k(
    const float* __restrict__ Q, const float* __restrict__ K, const float* __restrict__ V,
    const float* __restrict__ Wq, const float* __restrict__ Wk, const float* __restrict__ Wv,
    const float* __restrict__ Wo, unsigned short* __restrict__ dst) {
    unsigned gid  = blockIdx.x * 256u + threadIdx.x;   // 4M threads
    unsigned base = gid * 4u;                          // element index
    unsigned seg  = base >> 20;
    const float* src; unsigned off;
    if      (seg <  4u) { src = Q;  off = base; }
    else if (seg <  8u) { src = K;  off = base - (4u  << 20); }
    else if (seg < 12u) { src = V;  off = base - (8u  << 20); }
    else if (seg == 12u){ src = Wq; off = base - (12u << 20); }
    else if (seg == 13u){ src = Wk; off = base - (13u << 20); }
    else if (seg == 14u){ src = Wv; off = base - (14u << 20); }
    else                { src = Wo; off = base - (15u << 20); }
    float4 v = *reinterpret_cast<const float4*>(src + off);
    ushort4 o;
    o.x = f2bf(v.x); o.y = f2bf(v.y); o.z = f2bf(v.z); o.w = f2bf(v.w);
    *reinterpret_cast<ushort4*>(dst + base) = o;
}

// ------------------------------------------------------------- GEMM main loop
// C[m,n] = sum_k A[m,k]*B[n,k], 128x128 tile, BK=32, 4 waves (2x2), 64x64/wave.
// Double-buffered: stage tile ks+1 while computing tile ks; 1 barrier/step.
__device__ __forceinline__ void gemm_stage(
    const unsigned short* __restrict__ A, const unsigned short* __restrict__ Bm,
    int bm, int bn, int kt, unsigned short* As, unsigned short* Bs, int tid, int w) {
    #pragma unroll
    for (int is = 0; is < 2; ++is) {
        int g = is * 256 + tid;            // granule 0..511, 16B each
        int row = g >> 2, c = g & 3;       // 4 granules per 64B row
        gload_lds16(A  + (unsigned)(bm * 128 + row) * 1024 + kt + c * 8,
                    As + (unsigned)(is * 256 + w * 64) * 8);
        gload_lds16(Bm + (unsigned)(bn * 128 + row) * 1024 + kt + c * 8,
                    Bs + (unsigned)(is * 256 + w * 64) * 8);
    }
}

__device__ __forceinline__ void gemm_core(
    const unsigned short* __restrict__ A, const unsigned short* __restrict__ Bm,
    int bm, int bn, f32x4 acc[4][4],
    unsigned short (&As)[2][128 * 32], unsigned short (&Bs)[2][128 * 32]) {
    const int tid = threadIdx.x;
    const int w = tid >> 6, l = tid & 63, lg = l >> 4, lr = l & 15;
    const int wr = w >> 1, wc = w & 1;
    gemm_stage(A, Bm, bm, bn, 0, As[0], Bs[0], tid, w);
    __syncthreads();                                   // drains own vmcnt, then barrier
    for (int ks = 0; ks < 32; ++ks) {
        const int cur = ks & 1;
        if (ks + 1 < 32)                               // prefetch next K-tile
            gemm_stage(A, Bm, bm, bn, (ks + 1) * 32, As[cur ^ 1], Bs[cur ^ 1], tid, w);
        bf16x8 af[4], bfr[4];
        #pragma unroll
        for (int i = 0; i < 4; ++i)
            af[i]  = *reinterpret_cast<const bf16x8*>(&As[cur][(wr * 64 + i * 16 + lr) * 32 + lg * 8]);
        #pragma unroll
        for (int j = 0; j < 4; ++j)
            bfr[j] = *reinterpret_cast<const bf16x8*>(&Bs[cur][(wc * 64 + j * 16 + lr) * 32 + lg * 8]);
        #pragma unroll
        for (int i = 0; i < 4; ++i)
            #pragma unroll
            for (int j = 0; j < 4; ++j)
                acc[i][j] = __builtin_amdgcn_mfma_f32_16x16x32_bf16(af[i], bfr[j], acc[i][j], 0, 0, 0);
        __syncthreads();   // prior reads done + prefetch landed -> safe to swap
    }
}

// ------------------------------------------------- fused Q/K/V projections
// z=0: q = (Qb @ Wq^T + bq) * 0.125  -> qh [B,H,S,DK] bf16  (1/sqrt(DK) folded in)
// z=1: k = Kb @ Wk^T + bk            -> kh [B,H,S,DK] bf16
// z=2: v^T = Wv @ Vb^T               -> vt [B,H,DK,S] bf16  (A=Wv, B=Vb; bias by m)
__global__ __launch_bounds__(256) void proj_fused_k(
    const unsigned short* __restrict__ bfall,
    const float* __restrict__ bq, const float* __restrict__ bk, const float* __restrict__ bv,
    unsigned short* __restrict__ qh, unsigned short* __restrict__ kh,
    unsigned short* __restrict__ vt) {
    __shared__ __align__(16) unsigned short As[2][128 * 32], Bs[2][128 * 32];
    const unsigned M1 = 1u << 20;
    int bid = blockIdx.x;
    int z = bid >> 8, r = bid & 255;
    const unsigned short *A, *Bm; const float* bias; unsigned short* outp;
    int bm, bn;
    if (z == 0)      { A = bfall;           Bm = bfall + 12 * M1; bias = bq; outp = qh; bm = r >> 3; bn = r & 7; }
    else if (z == 1) { A = bfall + 4 * M1;  Bm = bfall + 13 * M1; bias = bk; outp = kh; bm = r >> 3; bn = r & 7; }
    else             { A = bfall + 14 * M1; Bm = bfall + 8 * M1;  bias = bv; outp = vt; bm = r >> 5; bn = r & 31; }

    f32x4 acc[4][4] = {};
    gemm_core(A, Bm, bm, bn, acc, As, Bs);

    const int tid = threadIdx.x;
    const int w = tid >> 6, l = tid & 63, lg = l >> 4, lr = l & 15;
    const int wr = w >> 1, wc = w & 1;
    #pragma unroll
    for (int i = 0; i < 4; ++i) {
        #pragma unroll
        for (int j = 0; j < 4; ++j) {
            int n = bn * 128 + wc * 64 + j * 16 + lr;
            #pragma unroll
            for (int rr = 0; rr < 4; ++rr) {
                int m = bm * 128 + wr * 64 + i * 16 + 4 * lg + rr;
                float v = acc[i][j][rr];
                if (z < 2) {
                    v += bias[n];
                    if (z == 0) v *= 0.125f;           // 1/sqrt(DK) folded into q
                    int b = m >> 11, s = m & 2047, h = n >> 6, d = n & 63;
                    outp[(((unsigned)(b * 16 + h) * 2048 + s) << 6) + d] = f2bf(v);
                } else {
                    v += bias[m];
                    int h = m >> 6, d = m & 63, b = n >> 11, s = n & 2047;
                    outp[(((unsigned)(b * 16 + h) << 6) + d) * 2048 + s] = f2bf(v);
                }
            }
        }
    }
}

// ------------------------------------------------------------ flash attention
// 1 wg per (bh, 64-row q block), 4 waves x 16 q rows. K/V double-buffered via
// global_load_lds with XOR-swizzled SOURCE (linear LDS dest), swizzled reads.
__device__ __forceinline__ void attn_stage(
    const unsigned short* __restrict__ khb, const unsigned short* __restrict__ vtb,
    int kb, unsigned short* KtB, unsigned short* VtB, int tid, int w) {
    #pragma unroll
    for (int is = 0; is < 2; ++is) {
        int g = is * 256 + tid;              // granule: 8 x 16B per 128B row
        int row = g >> 3, cp = g & 7;
        int ck = cp ^ (row & 7);             // inverse swizzle on SOURCE
        gload_lds16(khb + (unsigned)(kb + row) * 64 + ck * 8,
                    KtB + (unsigned)(is * 256 + w * 64) * 8);
        gload_lds16(vtb + (unsigned)row * S_ + kb + ck * 8,
                    VtB + (unsigned)(is * 256 + w * 64) * 8);
    }
}

__global__ __launch_bounds__(256) void attn_k(
    const unsigned short* __restrict__ qh, const unsigned short* __restrict__ kh,
    const unsigned short* __restrict__ vt, unsigned short* __restrict__ ctx) {
    __shared__ __align__(16) unsigned short Kt[2][64 * 64], Vt[2][64 * 64], Pb[4][16 * 64];
    const int bh = blockIdx.x, qi = blockIdx.y;
    const int b = bh >> 4, h = bh & 15;
    const int qb = (S_ - 64) - 64 * qi;          // heavy blocks dispatch first
    const int tid = threadIdx.x, w = tid >> 6, l = tid & 63, lg = l >> 4, lr = l & 15;
    const unsigned short* khb = kh + (unsigned)bh * S_ * 64;   // [key][dk]
    const unsigned short* vtb = vt + (unsigned)bh * 64 * S_;   // [dk][key]

    // Q fragments (A-operand), resident whole kernel. qh is pre-scaled by 1/8.
    const unsigned short* qrow = qh + ((unsigned)bh * S_ + qb + w * 16 + lr) * 64 + lg * 8;
    const bf16x8 aq0 = *reinterpret_cast<const bf16x8*>(qrow);
    const bf16x8 aq1 = *reinterpret_cast<const bf16x8*>(qrow + 32);

    f32x4 o[4] = {};
    float m_r[4], l_r[4];
    #pragma unroll
    for (int rr = 0; rr < 4; ++rr) { m_r[rr] = -1e30f; l_r[rr] = 0.f; }

    const int ntiles = qb / 64 + 1;
    attn_stage(khb, vtb, 0, Kt[0], Vt[0], tid, w);
    __syncthreads();
    for (int t = 0; t < ntiles; ++t) {
        const int cur = t & 1;
        if (t + 1 < ntiles)                      // prefetch next K/V tile
            attn_stage(khb, vtb, (t + 1) * 64, Kt[cur ^ 1], Vt[cur ^ 1], tid, w);
        const unsigned short* Kc = Kt[cur];
        const unsigned short* Vc = Vt[cur];

        // ---- S = Q K^T  (4 frags of 16q x 16key)
        f32x4 sf[4];
        __builtin_amdgcn_s_setprio(1);
        #pragma unroll
        for (int f = 0; f < 4; ++f) {
            f32x4 a = {};
            int row0 = f * 16 + lr;
            bf16x8 bk0 = *reinterpret_cast<const bf16x8*>(&Kc[row0 * 64 + ((lg + 0) ^ (row0 & 7)) * 8]);
            a = __builtin_amdgcn_mfma_f32_16x16x32_bf16(aq0, bk0, a, 0, 0, 0);
            bf16x8 bk1 = *reinterpret_cast<const bf16x8*>(&Kc[row0 * 64 + ((lg + 4) ^ (row0 & 7)) * 8]);
            a = __builtin_amdgcn_mfma_f32_16x16x32_bf16(aq1, bk1, a, 0, 0, 0);
            sf[f] = a;
        }
        __builtin_amdgcn_s_setprio(0);
        const bool diag = (t == ntiles - 1);
        float sc[4];
        #pragma unroll
        for (int rr = 0; rr < 4; ++rr) {
            float mv = -1e30f;
            #pragma unroll
            for (int f = 0; f < 4; ++f) {
                float v = sf[f][rr];             // scale pre-folded into q
                if (diag && (f * 16 + lr) > (w * 16 + 4 * lg + rr)) v = -1e30f;  // causal
                sf[f][rr] = v;
                mv = fmaxf(mv, v);
            }
            mv = fmaxf(mv, __shfl_xor(mv, 1));
            mv = fmaxf(mv, __shfl_xor(mv, 2));
            mv = fmaxf(mv, __shfl_xor(mv, 4));
            mv = fmaxf(mv, __shfl_xor(mv, 8));
            float mn = fmaxf(m_r[rr], mv);
            sc[rr] = __expf(m_r[rr] - mn);
            m_r[rr] = mn;
            float s = 0.f;
            #pragma unroll
            for (int f = 0; f < 4; ++f) {
                float p = __expf(sf[f][rr] - mn);
                sf[f][rr] = p;
                s += p;
            }
            s += __shfl_xor(s, 1); s += __shfl_xor(s, 2);
            s += __shfl_xor(s, 4); s += __shfl_xor(s, 8);
            l_r[rr] = l_r[rr] * sc[rr] + s;
        }
        #pragma unroll
        for (int f2 = 0; f2 < 4; ++f2)
            #pragma unroll
            for (int rr = 0; rr < 4; ++rr)
                o[f2][rr] *= sc[rr];

        // ---- P -> per-wave LDS (transpose to A-frag layout), swizzled
        unsigned short* Pw = &Pb[w][0];
        #pragma unroll
        for (int f = 0; f < 4; ++f) {
            int col = f * 16 + lr, ch = col >> 3, wi = col & 7;
            #pragma unroll
            for (int rr = 0; rr < 4; ++rr) {
                int row = 4 * lg + rr;
                Pw[row * 64 + ((ch ^ (row & 7)) << 3) + wi] = f2bf(sf[f][rr]);
            }
        }
        asm volatile("s_waitcnt lgkmcnt(0)" ::: "memory");   // writes visible (same-wave)
        bf16x8 ap0 = *reinterpret_cast<const bf16x8*>(&Pw[lr * 64 + ((lg + 0) ^ (lr & 7)) * 8]);
        bf16x8 ap1 = *reinterpret_cast<const bf16x8*>(&Pw[lr * 64 + ((lg + 4) ^ (lr & 7)) * 8]);

        // ---- O += P V   (V^T staged: B-frag is contiguous keys per d-row)
        __builtin_amdgcn_s_setprio(1);
        #pragma unroll
        for (int f2 = 0; f2 < 4; ++f2) {
            int row = f2 * 16 + lr;
            bf16x8 bv0 = *reinterpret_cast<const bf16x8*>(&Vc[row * 64 + ((lg + 0) ^ (row & 7)) * 8]);
            o[f2] = __builtin_amdgcn_mfma_f32_16x16x32_bf16(ap0, bv0, o[f2], 0, 0, 0);
            bf16x8 bv1 = *reinterpret_cast<const bf16x8*>(&Vc[row * 64 + ((lg + 4) ^ (row & 7)) * 8]);
            o[f2] = __builtin_amdgcn_mfma_f32_16x16x32_bf16(ap1, bv1, o[f2], 0, 0, 0);
        }
        __builtin_amdgcn_s_setprio(0);
        __syncthreads();   // P/K/V reads done + prefetch landed -> safe to swap
    }

    // ---- epilogue: ctx [B,S,D] bf16
    #pragma unroll
    for (int f2 = 0; f2 < 4; ++f2) {
        #pragma unroll
        for (int rr = 0; rr < 4; ++rr) {
            int s = qb + w * 16 + 4 * lg + rr;
            float v = o[f2][rr] / l_r[rr];
            ctx[(((unsigned)(b * S_ + s) * H_ + h) << 6) + f2 * 16 + lr] = f2bf(v);
        }
    }
}

// ------------------------------------------------------------ final projection
__global__ __launch_bounds__(256) void final_k(
    const unsigned short* __restrict__ ctx, const unsigned short* __restrict__ Wob,
    const float* __restrict__ bo, float* __restrict__ out) {
    __shared__ __align__(16) unsigned short As[2][128 * 32], Bs[2][128 * 32];
    int bid = blockIdx.x;
    int bm = bid >> 3, bn = bid & 7;
    f32x4 acc[4][4] = {};
    gemm_core(ctx, Wob, bm, bn, acc, As, Bs);
    const int tid = threadIdx.x;
    const int w = tid >> 6, l = tid & 63, lg = l >> 4, lr = l & 15;
    const int wr = w >> 1, wc = w & 1;
    #pragma unroll
    for (int i = 0; i < 4; ++i) {
        #pragma unroll
        for (int j = 0; j < 4; ++j) {
            int n = bn * 128 + wc * 64 + j * 16 + lr;
            float bn_v = bo[n];
            #pragma unroll
            for (int rr = 0; rr < 4; ++rr) {
                int m = bm * 128 + wr * 64 + i * 16 + 4 * lg + rr;
                out[(unsigned)m * 1024 + n] = acc[i][j][rr] + bn_v;
            }
        }
    }
}

// ---------------------------------------------------------------------- launch
extern "C" void kernel_launch(void* const* d_in, const int* in_sizes, int n_in,
                              void* d_out, int out_size, void* d_ws, size_t ws_size,
                              hipStream_t stream) {
    const float* Q  = (const float*)d_in[0];
    const float* K  = (const float*)d_in[1];
    const float* V  = (const float*)d_in[2];
    // d_in[3] = mask (tril) — causal handled analytically
    const float* Wq = (const float*)d_in[4];
    const float* bq = (const float*)d_in[5];
    const float* Wk = (const float*)d_in[6];
    const float* bk = (const float*)d_in[7];
    const float* Wv = (const float*)d_in[8];
    const float* bv = (const float*)d_in[9];
    const float* Wo = (const float*)d_in[10];
    const float* bo = (const float*)d_in[11];
    float* out = (float*)d_out;

    unsigned short* ws = (unsigned short*)d_ws;
    const unsigned M1 = 1u << 20;
    // ws layout (elements): [0,16M) bf16 casts of Q,K,V,Wq,Wk,Wv,Wo
    //                       [16M,20M) qh  [20M,24M) kh  [24M,28M) vt
    //                       ctx overlays [0,4M) (Qb dead after projections)
    unsigned short* bfall = ws;
    unsigned short* qh    = ws + (size_t)16 * M1;
    unsigned short* khp   = ws + (size_t)20 * M1;
    unsigned short* vtp   = ws + (size_t)24 * M1;
    unsigned short* ctx   = ws;                      // reuse Qb region
    // total: 28M elems = 56 MB of d_ws

    hipLaunchKernelGGL(cast_all_k, dim3(16384), dim3(256), 0, stream,
                       Q, K, V, Wq, Wk, Wv, Wo, bfall);
    hipLaunchKernelGGL(proj_fused_k, dim3(768), dim3(256), 0, stream,
                       bfall, bq, bk, bv, qh, khp, vtp);
    hipLaunchKernelGGL(attn_k, dim3(32, 32), dim3(256), 0, stream,
                       qh, khp, vtp, ctx);
    hipLaunchKernelGGL(final_k, dim3(256), dim3(256), 0, stream,
                       ctx, bfall + (size_t)15 * M1, bo, out);
}

// Round 7
// 246.257 us; speedup vs baseline: 1.0857x; 1.0857x over previous
//
#include <hip/hip_runtime.h>

// MHA forward, MI355X gfx950.
// B=2, S=2048, D=1024, H=16, DK=64. fp32 in/out, bf16 MFMA compute inside.
#define B_  2
#define S_  2048
#define D_  1024
#define H_  16
#define DK_ 64

using bf16x8 = __attribute__((ext_vector_type(8))) short;   // 8 bf16 in 4 VGPRs
using f32x4  = __attribute__((ext_vector_type(4))) float;

__device__ __forceinline__ unsigned short f2bf(float f) {
    unsigned u = __builtin_bit_cast(unsigned, f);
    u += 0x7FFFu + ((u >> 16) & 1u);            // RNE
    return (unsigned short)(u >> 16);
}

__device__ __forceinline__ unsigned cvt_pk_bf16(float lo, float hi) {
    unsigned r;
    asm("v_cvt_pk_bf16_f32 %0, %1, %2" : "=v"(r) : "v"(lo), "v"(hi));
    return r;
}

__device__ __forceinline__ float exp2_fast(float x) {
    float r;
    asm("v_exp_f32 %0, %1" : "=v"(r) : "v"(x));
    return r;
}

__device__ __forceinline__ void gload_lds16(const unsigned short* gsrc, unsigned short* ldst) {
    // 16B direct global->LDS. LDS dest must be wave-uniform base (+lane*16 implicit).
    __builtin_amdgcn_global_load_lds((const __attribute__((address_space(1))) void*)gsrc,
                                     (__attribute__((address_space(3))) void*)ldst, 16, 0, 0);
}

// ---------------------------------------------------------------- cast kernel
// Segments (1M-elem units): [0,4)Q [4,8)K [8,12)V [12]Wq [13]Wk [14]Wv [15]Wo
__global__ __launch_bounds__(256) void cast_all_k(
    const float* __restrict__ Q, const float* __restrict__ K, const float* __restrict__ V,
    const float* __restrict__ Wq, const float* __restrict__ Wk, const float* __restrict__ Wv,
    const float* __restrict__ Wo, unsigned short* __restrict__ dst) {
    unsigned gid  = blockIdx.x * 256u + threadIdx.x;   // 4M threads
    unsigned base = gid * 4u;                          // element index
    unsigned seg  = base >> 20;
    const float* src; unsigned off;
    if      (seg <  4u) { src = Q;  off = base; }
    else if (seg <  8u) { src = K;  off = base - (4u  << 20); }
    else if (seg < 12u) { src = V;  off = base - (8u  << 20); }
    else if (seg == 12u){ src = Wq; off = base - (12u << 20); }
    else if (seg == 13u){ src = Wk; off = base - (13u << 20); }
    else if (seg == 14u){ src = Wv; off = base - (14u << 20); }
    else                { src = Wo; off = base - (15u << 20); }
    float4 v = *reinterpret_cast<const float4*>(src + off);
    ushort4 o;
    o.x = f2bf(v.x); o.y = f2bf(v.y); o.z = f2bf(v.z); o.w = f2bf(v.w);
    *reinterpret_cast<ushort4*>(dst + base) = o;
}

// ------------------------------------------------------------- GEMM main loop
// C[m,n] = sum_k A[m,k]*B[n,k], 128x128 tile, BK=32, 4 waves (2x2), 64x64/wave.
// Double-buffered: stage tile ks+1 while computing tile ks; 1 barrier/step.
__device__ __forceinline__ void gemm_stage(
    const unsigned short* __restrict__ A, const unsigned short* __restrict__ Bm,
    int bm, int bn, int kt, unsigned short* As, unsigned short* Bs, int tid, int w) {
    #pragma unroll
    for (int is = 0; is < 2; ++is) {
        int g = is * 256 + tid;            // granule 0..511, 16B each
        int row = g >> 2, c = g & 3;       // 4 granules per 64B row
        gload_lds16(A  + (unsigned)(bm * 128 + row) * 1024 + kt + c * 8,
                    As + (unsigned)(is * 256 + w * 64) * 8);
        gload_lds16(Bm + (unsigned)(bn * 128 + row) * 1024 + kt + c * 8,
                    Bs + (unsigned)(is * 256 + w * 64) * 8);
    }
}

__device__ __forceinline__ void gemm_core(
    const unsigned short* __restrict__ A, const unsigned short* __restrict__ Bm,
    int bm, int bn, f32x4 acc[4][4],
    unsigned short (&As)[2][128 * 32], unsigned short (&Bs)[2][128 * 32]) {
    const int tid = threadIdx.x;
    const int w = tid >> 6, l = tid & 63, lg = l >> 4, lr = l & 15;
    const int wr = w >> 1, wc = w & 1;
    gemm_stage(A, Bm, bm, bn, 0, As[0], Bs[0], tid, w);
    __syncthreads();                                   // drains own vmcnt, then barrier
    for (int ks = 0; ks < 32; ++ks) {
        const int cur = ks & 1;
        if (ks + 1 < 32)                               // prefetch next K-tile
            gemm_stage(A, Bm, bm, bn, (ks + 1) * 32, As[cur ^ 1], Bs[cur ^ 1], tid, w);
        bf16x8 af[4], bfr[4];
        #pragma unroll
        for (int i = 0; i < 4; ++i)
            af[i]  = *reinterpret_cast<const bf16x8*>(&As[cur][(wr * 64 + i * 16 + lr) * 32 + lg * 8]);
        #pragma unroll
        for (int j = 0; j < 4; ++j)
            bfr[j] = *reinterpret_cast<const bf16x8*>(&Bs[cur][(wc * 64 + j * 16 + lr) * 32 + lg * 8]);
        #pragma unroll
        for (int i = 0; i < 4; ++i)
            #pragma unroll
            for (int j = 0; j < 4; ++j)
                acc[i][j] = __builtin_amdgcn_mfma_f32_16x16x32_bf16(af[i], bfr[j], acc[i][j], 0, 0, 0);
        __syncthreads();   // prior reads done + prefetch landed -> safe to swap
    }
}

// ------------------------------------------------- fused Q/K/V projections
// z=0: q = (Qb @ Wq^T + bq) * 0.125*log2e -> qh [B,H,S,DK] bf16 (scale+exp2 fold)
// z=1: k = Kb @ Wk^T + bk                 -> kh [B,H,S,DK] bf16
// z=2: v^T = Wv @ Vb^T                    -> vt [B,H,DK,S] bf16 (A=Wv, B=Vb; bias by m)
// XCD-chunked swizzle (T1): 768 wgs, blocks on XCD x get contiguous wgid chunk
// -> each A-panel fetched from HBM once chip-wide; B-panels L2-resident.
__global__ __launch_bounds__(256) void proj_fused_k(
    const unsigned short* __restrict__ bfall,
    const float* __restrict__ bq, const float* __restrict__ bk, const float* __restrict__ bv,
    unsigned short* __restrict__ qh, unsigned short* __restrict__ kh,
    unsigned short* __restrict__ vt) {
    __shared__ __align__(16) unsigned short As[2][128 * 32], Bs[2][128 * 32];
    const unsigned M1 = 1u << 20;
    int bid = blockIdx.x;
    int wgid = (bid & 7) * 96 + (bid >> 3);            // bijective, 768 = 8*96
    int z = wgid >> 8, r = wgid & 255;
    const unsigned short *A, *Bm; const float* bias; unsigned short* outp;
    int bm, bn;
    if (z == 0)      { A = bfall;           Bm = bfall + 12 * M1; bias = bq; outp = qh; bm = r >> 3; bn = r & 7; }
    else if (z == 1) { A = bfall + 4 * M1;  Bm = bfall + 13 * M1; bias = bk; outp = kh; bm = r >> 3; bn = r & 7; }
    else             { A = bfall + 14 * M1; Bm = bfall + 8 * M1;  bias = bv; outp = vt; bm = r >> 5; bn = r & 31; }

    f32x4 acc[4][4] = {};
    gemm_core(A, Bm, bm, bn, acc, As, Bs);

    const int tid = threadIdx.x;
    const int w = tid >> 6, l = tid & 63, lg = l >> 4, lr = l & 15;
    const int wr = w >> 1, wc = w & 1;
    #pragma unroll
    for (int i = 0; i < 4; ++i) {
        #pragma unroll
        for (int j = 0; j < 4; ++j) {
            int n = bn * 128 + wc * 64 + j * 16 + lr;
            #pragma unroll
            for (int rr = 0; rr < 4; ++rr) {
                int m = bm * 128 + wr * 64 + i * 16 + 4 * lg + rr;
                float v = acc[i][j][rr];
                if (z < 2) {
                    v += bias[n];
                    if (z == 0) v *= 0.18033688f;      // (1/sqrt(DK)) * log2(e)
                    int b = m >> 11, s = m & 2047, h = n >> 6, d = n & 63;
                    outp[(((unsigned)(b * 16 + h) * 2048 + s) << 6) + d] = f2bf(v);
                } else {
                    v += bias[m];
                    int h = m >> 6, d = m & 63, b = n >> 11, s = n & 2047;
                    outp[(((unsigned)(b * 16 + h) << 6) + d) * 2048 + s] = f2bf(v);
                }
            }
        }
    }
}

// ------------------------------------------------------------ flash attention
// 1 wg per (bh, 64-row q block), 4 waves x 16 q rows. Swapped QK^T (S^T =
// mfma(K,Q)) makes the key-axis reductions lane-local: per-lane scalar m/l,
// 2 shuffles per reduction, packed b64 P-writes, PV as O^T = mfma(V^T, P).
__device__ __forceinline__ void attn_stage(
    const unsigned short* __restrict__ khb, const unsigned short* __restrict__ vtb,
    int kb, unsigned short* KtB, unsigned short* VtB, int tid, int w) {
    #pragma unroll
    for (int is = 0; is < 2; ++is) {
        int g = is * 256 + tid;              // granule: 8 x 16B per 128B row
        int row = g >> 3, cp = g & 7;
        int ck = cp ^ (row & 7);             // inverse swizzle on SOURCE
        gload_lds16(khb + (unsigned)(kb + row) * 64 + ck * 8,
                    KtB + (unsigned)(is * 256 + w * 64) * 8);
        gload_lds16(vtb + (unsigned)row * S_ + kb + ck * 8,
                    VtB + (unsigned)(is * 256 + w * 64) * 8);
    }
}

__global__ __launch_bounds__(256) void attn_k(
    const unsigned short* __restrict__ qh, const unsigned short* __restrict__ kh,
    const unsigned short* __restrict__ vt, unsigned short* __restrict__ ctx) {
    __shared__ __align__(16) unsigned short Kt[2][64 * 64], Vt[2][64 * 64], Pb[4][16 * 64];
    const int bh = blockIdx.x, qi = blockIdx.y;
    const int b = bh >> 4, h = bh & 15;
    const int qb = (S_ - 64) - 64 * qi;          // heavy blocks dispatch first
    const int tid = threadIdx.x, w = tid >> 6, l = tid & 63, lg = l >> 4, lr = l & 15;
    const unsigned short* khb = kh + (unsigned)bh * S_ * 64;   // [key][dk]
    const unsigned short* vtb = vt + (unsigned)bh * 64 * S_;   // [dk][key]

    // Q fragments (B-operand now), resident whole kernel. qh pre-scaled by 0.125*log2e.
    const unsigned short* qrow = qh + ((unsigned)bh * S_ + qb + w * 16 + lr) * 64 + lg * 8;
    const bf16x8 bq0 = *reinterpret_cast<const bf16x8*>(qrow);        // dk[lg*8..+7]
    const bf16x8 bq1 = *reinterpret_cast<const bf16x8*>(qrow + 32);   // dk[32+lg*8..]

    // o[f2][rr] = O^T[d = f2*16 + lg*4 + rr][q = lr]; per-lane scalar m/l (q = lr).
    f32x4 o[4] = {};
    float m_r = -1e30f, l_r = 0.f;
    const int swz = (lr & 7) << 4;               // P-LDS byte swizzle for this lane's q-row

    const int ntiles = qb / 64 + 1;
    attn_stage(khb, vtb, 0, Kt[0], Vt[0], tid, w);
    __syncthreads();
    for (int t = 0; t < ntiles; ++t) {
        const int cur = t & 1;
        if (t + 1 < ntiles)                      // prefetch next K/V tile
            attn_stage(khb, vtb, (t + 1) * 64, Kt[cur ^ 1], Vt[cur ^ 1], tid, w);
        const unsigned short* Kc = Kt[cur];
        const unsigned short* Vc = Vt[cur];

        // ---- S^T[key][q] = mfma(K, Q): lane holds keys {16f+4lg+rr} of q-row lr
        f32x4 sf[4];
        __builtin_amdgcn_s_setprio(1);
        #pragma unroll
        for (int f = 0; f < 4; ++f) {
            f32x4 a = {};
            int row0 = f * 16 + lr;
            bf16x8 ak0 = *reinterpret_cast<const bf16x8*>(&Kc[row0 * 64 + ((lg + 0) ^ (row0 & 7)) * 8]);
            a = __builtin_amdgcn_mfma_f32_16x16x32_bf16(ak0, bq0, a, 0, 0, 0);
            bf16x8 ak1 = *reinterpret_cast<const bf16x8*>(&Kc[row0 * 64 + ((lg + 4) ^ (row0 & 7)) * 8]);
            a = __builtin_amdgcn_mfma_f32_16x16x32_bf16(ak1, bq1, a, 0, 0, 0);
            sf[f] = a;
        }
        __builtin_amdgcn_s_setprio(0);

        // ---- online softmax (log2 domain), key-axis is lane-local
        if (t == ntiles - 1) {                   // causal mask on diagonal tile
            #pragma unroll
            for (int f = 0; f < 4; ++f)
                #pragma unroll
                for (int rr = 0; rr < 4; ++rr)
                    if (16 * f + 4 * lg + rr > w * 16 + lr) sf[f][rr] = -1e30f;
        }
        float pmax = -1e30f;
        #pragma unroll
        for (int f = 0; f < 4; ++f)
            #pragma unroll
            for (int rr = 0; rr < 4; ++rr)
                pmax = fmaxf(pmax, sf[f][rr]);
        pmax = fmaxf(pmax, __shfl_xor(pmax, 16));
        pmax = fmaxf(pmax, __shfl_xor(pmax, 32));
        if (!__all(pmax <= m_r + 11.5f)) {       // T13 defer-max (11.5 = 8*log2e)
            float mn = fmaxf(m_r, pmax);
            float sc = exp2_fast(m_r - mn);
            #pragma unroll
            for (int f2 = 0; f2 < 4; ++f2)
                #pragma unroll
                for (int rr = 0; rr < 4; ++rr)
                    o[f2][rr] *= sc;
            l_r *= sc;
            m_r = mn;
        }
        float s = 0.f;
        #pragma unroll
        for (int f = 0; f < 4; ++f)
            #pragma unroll
            for (int rr = 0; rr < 4; ++rr) {
                float p = exp2_fast(sf[f][rr] - m_r);
                sf[f][rr] = p;
                s += p;
            }
        s += __shfl_xor(s, 16);
        s += __shfl_xor(s, 32);
        l_r += s;

        // ---- P -> per-wave LDS [q=lr][key], packed b64 writes, XOR-swizzled
        char* Pw = (char*)&Pb[w][0];
        #pragma unroll
        for (int f = 0; f < 4; ++f) {
            uint2 u;
            u.x = cvt_pk_bf16(sf[f][0], sf[f][1]);
            u.y = cvt_pk_bf16(sf[f][2], sf[f][3]);
            *reinterpret_cast<uint2*>(Pw + lr * 128 + ((32 * f + 8 * lg) ^ swz)) = u;
        }
        asm volatile("s_waitcnt lgkmcnt(0)" ::: "memory");   // same-wave DS order
        bf16x8 bp0 = *reinterpret_cast<const bf16x8*>(Pw + lr * 128 + ((16 * lg) ^ swz));
        bf16x8 bp1 = *reinterpret_cast<const bf16x8*>(Pw + lr * 128 + ((64 + 16 * lg) ^ swz));

        // ---- O^T += mfma(V^T, P)
        __builtin_amdgcn_s_setprio(1);
        #pragma unroll
        for (int f2 = 0; f2 < 4; ++f2) {
            int row = f2 * 16 + lr;
            bf16x8 av0 = *reinterpret_cast<const bf16x8*>(&Vc[row * 64 + ((lg + 0) ^ (row & 7)) * 8]);
            o[f2] = __builtin_amdgcn_mfma_f32_16x16x32_bf16(av0, bp0, o[f2], 0, 0, 0);
            bf16x8 av1 = *reinterpret_cast<const bf16x8*>(&Vc[row * 64 + ((lg + 4) ^ (row & 7)) * 8]);
            o[f2] = __builtin_amdgcn_mfma_f32_16x16x32_bf16(av1, bp1, o[f2], 0, 0, 0);
        }
        __builtin_amdgcn_s_setprio(0);
        __syncthreads();   // P/K/V reads done + prefetch landed -> safe to swap
    }

    // ---- epilogue: ctx [B,S,H,DK] bf16; lane writes 4x 8B packed (d contiguous)
    const float inv = 1.f / l_r;
    const int s_row = qb + w * 16 + lr;
    unsigned short* cbase = ctx + (((unsigned)(b * S_ + s_row) * H_ + h) << 6);
    #pragma unroll
    for (int f2 = 0; f2 < 4; ++f2) {
        uint2 u;
        u.x = cvt_pk_bf16(o[f2][0] * inv, o[f2][1] * inv);
        u.y = cvt_pk_bf16(o[f2][2] * inv, o[f2][3] * inv);
        *reinterpret_cast<uint2*>(cbase + f2 * 16 + lg * 4) = u;
    }
}

// ------------------------------------------------------------ final projection
__global__ __launch_bounds__(256) void final_k(
    const unsigned short* __restrict__ ctx, const unsigned short* __restrict__ Wob,
    const float* __restrict__ bo, float* __restrict__ out) {
    __shared__ __align__(16) unsigned short As[2][128 * 32], Bs[2][128 * 32];
    int bid = blockIdx.x;
    int wgid = (bid & 7) * 32 + (bid >> 3);            // XCD-chunked, 256 = 8*32
    int bm = wgid >> 3, bn = wgid & 7;
    f32x4 acc[4][4] = {};
    gemm_core(ctx, Wob, bm, bn, acc, As, Bs);
    const int tid = threadIdx.x;
    const int w = tid >> 6, l = tid & 63, lg = l >> 4, lr = l & 15;
    const int wr = w >> 1, wc = w & 1;
    #pragma unroll
    for (int i = 0; i < 4; ++i) {
        #pragma unroll
        for (int j = 0; j < 4; ++j) {
            int n = bn * 128 + wc * 64 + j * 16 + lr;
            float bn_v = bo[n];
            #pragma unroll
            for (int rr = 0; rr < 4; ++rr) {
                int m = bm * 128 + wr * 64 + i * 16 + 4 * lg + rr;
                out[(unsigned)m * 1024 + n] = acc[i][j][rr] + bn_v;
            }
        }
    }
}

// ---------------------------------------------------------------------- launch
extern "C" void kernel_launch(void* const* d_in, const int* in_sizes, int n_in,
                              void* d_out, int out_size, void* d_ws, size_t ws_size,
                              hipStream_t stream) {
    const float* Q  = (const float*)d_in[0];
    const float* K  = (const float*)d_in[1];
    const float* V  = (const float*)d_in[2];
    // d_in[3] = mask (tril) — causal handled analytically
    const float* Wq = (const float*)d_in[4];
    const float* bq = (const float*)d_in[5];
    const float* Wk = (const float*)d_in[6];
    const float* bk = (const float*)d_in[7];
    const float* Wv = (const float*)d_in[8];
    const float* bv = (const float*)d_in[9];
    const float* Wo = (const float*)d_in[10];
    const float* bo = (const float*)d_in[11];
    float* out = (float*)d_out;

    unsigned short* ws = (unsigned short*)d_ws;
    const unsigned M1 = 1u << 20;
    // ws layout (elements): [0,16M) bf16 casts of Q,K,V,Wq,Wk,Wv,Wo
    //                       [16M,20M) qh  [20M,24M) kh  [24M,28M) vt
    //                       ctx overlays [0,4M) (Qb dead after projections)
    unsigned short* bfall = ws;
    unsigned short* qh    = ws + (size_t)16 * M1;
    unsigned short* khp   = ws + (size_t)20 * M1;
    unsigned short* vtp   = ws + (size_t)24 * M1;
    unsigned short* ctx   = ws;                      // reuse Qb region
    // total: 28M elems = 56 MB of d_ws

    hipLaunchKernelGGL(cast_all_k, dim3(16384), dim3(256), 0, stream,
                       Q, K, V, Wq, Wk, Wv, Wo, bfall);
    hipLaunchKernelGGL(proj_fused_k, dim3(768), dim3(256), 0, stream,
                       bfall, bq, bk, bv, qh, khp, vtp);
    hipLaunchKernelGGL(attn_k, dim3(32, 32), dim3(256), 0, stream,
                       qh, khp, vtp, ctx);
    hipLaunchKernelGGL(final_k, dim3(256), dim3(256), 0, stream,
                       ctx, bfall + (size_t)15 * M1, bo, out);
}